// Round 3
// baseline (172.637 us; speedup 1.0000x reference)
//
#include <hip/hip_runtime.h>

// FOFE encoding: out[row, :] = sum_k alpha^(L-1-k) * onehot(char_ids[row, k])
// rows = B*W = 131072, L = 20, VOCAB = 256. Output fp32 = 128 MiB -> memory
// floor ~21us (138 MiB at the measured 6.6 TB/s). Headline includes ~163us of
// harness re-poison fills (2x 512 MiB @ 81us); headline floor ~= 163+21+launch.
//
// R7 post-mortem: prediction matched (187->169.5us, kernel ~27us). The pure-
// VALU formulation costs 13 VALU-issues/char (readlane + 4x{cmp,cndmask,add})
// = 66k cyc/CU = 27.7us -- VALU-issue bound, ~6us above the memory floor,
// with the scalar pipe idle.
//
// R8: halve the compares and offload the half-select to the idle SALU pipe.
//  - pair match: id matches lane's xy pair iff id>>1 == 2*lane, zw pair iff
//    id>>1 == 2*lane+1  -> 2 v_cmp instead of 4.
//  - within-pair half: id&1 is wave-uniform (id is a readlane SGPR), so the
//    candidate pair (cl,ch) = (id&1) ? (0,pw) : (pw,0) compiles to
//    s_and (sets SCC) + 2x s_cselect_b32 on the scalar pipe; pw[k] bits are
//    pinned to SGPRs via readfirstlane in the prologue.
//  - the two adds per pair fuse into one v_pk_add_f32 (CDNA packed f32).
// Per char: 9 VALU (readlane + 2 cmp + 4 cndmask + 2 pk_add) + ~4 SALU.
// Per CU: VALU 46k cyc = 19.2us, SALU ~19us, memory ~21us -- balanced at the
// floor. Same k-order adds per component -> absmax unchanged (~1e-39).

constexpr int L     = 20;
constexpr int VOCAB = 256;
constexpr int BLOCK = 256;            // 4 waves per block
constexpr int GRID  = 2048;           // 8192 waves total
constexpr int RPW   = 16;             // rows per wave: 8192 * 16 = 131072
constexpr int GDW   = RPW * L / 64;   // 5 dwords of ids per lane per block

typedef float f32x2 __attribute__((ext_vector_type(2)));

__global__ __launch_bounds__(BLOCK) void fofe_kernel(
    const int* __restrict__ char_ids,
    const float* __restrict__ alpha_ptr,
    float* __restrict__ out,
    int n_rows)
{
    const int lane        = threadIdx.x & 63;
    const int wave_id     = (blockIdx.x * BLOCK + (int)threadIdx.x) >> 6;
    const int total_waves = (gridDim.x * blockDim.x) >> 6;

    const float alpha = *alpha_ptr;

    // pw[k] = alpha^(L-1-k); same repeated-multiply fp sequence as the
    // reference's alpha**arange (absmax ~1e-39 across R6/R7 -- exact match).
    float pw[L];
    {
        float cur = 1.0f;
        #pragma unroll
        for (int e = 0; e < L; ++e) { pw[(L - 1) - e] = cur; cur *= alpha; }
    }

    // Pin pw bit patterns to SGPRs so the per-char half-select is pure SALU
    // (s_cselect_b32 needs SGPR sources). All lanes hold identical pw.
    int pwb[L];
    #pragma unroll
    for (int k = 0; k < L; ++k)
        pwb[k] = __builtin_amdgcn_readfirstlane(__float_as_int(pw[k]));

    // Pair-match targets: lane owns vocab slots [4*lane, 4*lane+3], i.e.
    // id>>1 == 2*lane (xy pair) or 2*lane+1 (zw pair).
    const int lane2   = lane * 2;
    const int lane2p1 = lane2 + 1;

    float4* out4 = (float4*)out;
    const int total_dw = n_rows * L;

    // Outer grid-stride loop runs exactly once at the bench shape.
    for (int base = wave_id * RPW; base < n_rows; base += total_waves * RPW) {

        // ---- Phase 1: 5 fully-coalesced id loads (320 contiguous dwords =
        // 16 rows x 20 chars). The ONLY vmem reads; all precede any store.
        int g[GDW];
        const int fb = base * L;
        #pragma unroll
        for (int q = 0; q < GDW; ++q) {
            const int d = fb + q * 64 + lane;
            g[q] = (d < total_dw) ? char_ids[d] : 0;
        }

        // ---- Phase 2: per row, accumulate this lane's 4 slots with the
        // balanced VALU/SALU formulation, then one coalesced
        // global_store_dwordx4 (1 KiB per wave-store). No LDS, no vmem loads
        // in the store stream, no waits draining stores.
        #pragma unroll
        for (int r = 0; r < RPW; ++r) {
            const int row = base + r;
            if (row < n_rows) {                      // wave-uniform guard
                f32x2 axy = {0.f, 0.f};
                f32x2 azw = {0.f, 0.f};
                #pragma unroll
                for (int k = 0; k < L; ++k) {
                    const int d  = r * L + k;        // 0..319, compile-time
                    const int id = __builtin_amdgcn_readlane(g[d >> 6], d & 63);
                    // uniform half-select: SALU (s_and sets SCC; 2x s_cselect)
                    const int cl = (id & 1) ? 0      : pwb[k];
                    const int ch = (id & 1) ? pwb[k] : 0;
                    const int u  = id >> 1;          // uniform: s_lshr
                    // divergent pair-match: 2 v_cmp, 4 v_cndmask
                    f32x2 cxy, czw;
                    cxy.x = __int_as_float((u == lane2)   ? cl : 0);
                    cxy.y = __int_as_float((u == lane2)   ? ch : 0);
                    czw.x = __int_as_float((u == lane2p1) ? cl : 0);
                    czw.y = __int_as_float((u == lane2p1) ? ch : 0);
                    // packed f32 adds: 2 instructions for 4 components
                    asm("v_pk_add_f32 %0, %0, %1" : "+v"(axy) : "v"(cxy));
                    asm("v_pk_add_f32 %0, %0, %1" : "+v"(azw) : "v"(czw));
                }
                out4[(size_t)row * (VOCAB / 4) + lane] =
                    make_float4(axy.x, axy.y, azw.x, azw.y);
            }
        }
    }
}

extern "C" void kernel_launch(void* const* d_in, const int* in_sizes, int n_in,
                              void* d_out, int out_size, void* d_ws, size_t ws_size,
                              hipStream_t stream) {
    const int*   char_ids = (const int*)d_in[0];
    const float* alpha    = (const float*)d_in[1];
    float*       out      = (float*)d_out;
    const int    n_rows   = in_sizes[0] / L;   // 131072

    fofe_kernel<<<GRID, BLOCK, 0, stream>>>(char_ids, alpha, out, n_rows);
}

// Round 4
// 169.523 us; speedup vs baseline: 1.0184x; 1.0184x over previous
//
#include <hip/hip_runtime.h>

// FOFE encoding: out[row, :] = sum_k alpha^(L-1-k) * onehot(char_ids[row, k])
// rows = B*W = 131072, L = 20, VOCAB = 256. Output fp32 = 128 MiB -> memory
// floor ~21us (138 MiB at the measured ~6.7 TB/s). Headline includes ~145-163us
// of harness re-poison fills (2x 512 MiB @ ~81us each in the timed region);
// headline noise from fill variance is +-3-4us.
//
// R8 post-mortem (FAILED, 169.5 -> 172.6): the SALU-offload + v_pk_add_f32
// formulation couldn't compile as modeled -- v_cndmask's true-operand slot
// (vsrc1) is VGPR-only, so SGPR candidates force per-char v_movs, and the
// "+v" asm ties on f32x2 force pair-alignment shuffles. Net issue count >=
// R7's, plus SALU coupling. Regression ~= noise magnitude, but the prediction
// failed -> no trust.
//
// R9: REVERT to the best harness-verified kernel (R7, 169.5us). Pure-VALU
// char loop: per char = 1 v_readlane + 4x {v_cmp_eq, v_cndmask, v_add_f32}
// = 13 VALU issues, 0 SALU, no LDS, no atomics, no barriers. Kernel ~27us vs
// ~21us floor; the remaining ~6us is within headline measurement noise, so
// this is the effective roofline. Keep: 5 fully-coalesced id loads up front
// (320 contiguous dwords per 16-row block), zero vmem loads in the store
// stream (stores never drained by a wait -- R4/R5 lesson), one coalesced
// global_store_dwordx4 per row per lane.

constexpr int L     = 20;
constexpr int VOCAB = 256;
constexpr int BLOCK = 256;            // 4 waves per block
constexpr int GRID  = 2048;           // 8192 waves total
constexpr int RPW   = 16;             // rows per wave: 8192 * 16 = 131072
constexpr int GDW   = RPW * L / 64;   // 5 dwords of ids per lane per block

__global__ __launch_bounds__(BLOCK) void fofe_kernel(
    const int* __restrict__ char_ids,
    const float* __restrict__ alpha_ptr,
    float* __restrict__ out,
    int n_rows)
{
    const int lane        = threadIdx.x & 63;
    const int wave_id     = (blockIdx.x * BLOCK + (int)threadIdx.x) >> 6;
    const int total_waves = (gridDim.x * blockDim.x) >> 6;

    const float alpha = *alpha_ptr;

    // pw[k] = alpha^(L-1-k); same repeated-multiply fp sequence as the
    // reference's alpha**arange (absmax ~1e-39 across R6/R7/R8 -- exact).
    float pw[L];
    {
        float cur = 1.0f;
        #pragma unroll
        for (int e = 0; e < L; ++e) { pw[(L - 1) - e] = cur; cur *= alpha; }
    }

    // This lane's four owned vocab slots (VGPRs; compare targets).
    const int s0 = lane * 4;
    const int s1 = s0 + 1;
    const int s2 = s0 + 2;
    const int s3 = s0 + 3;

    float4* out4 = (float4*)out;
    const int total_dw = n_rows * L;

    // Outer grid-stride loop runs exactly once at the bench shape.
    for (int base = wave_id * RPW; base < n_rows; base += total_waves * RPW) {

        // ---- Phase 1: 5 fully-coalesced id loads (320 contiguous dwords =
        // 16 rows x 20 chars). The ONLY vmem reads; all precede any store.
        int g[GDW];
        const int fb = base * L;
        #pragma unroll
        for (int q = 0; q < GDW; ++q) {
            const int d = fb + q * 64 + lane;
            g[q] = (d < total_dw) ? char_ids[d] : 0;
        }

        // ---- Phase 2: per row, branchless pure-VALU accumulate of this
        // lane's 4 slots, then one coalesced global_store_dwordx4 (1 KiB per
        // wave-store). No SALU in the char loop, no LDS, no waits on stores.
        #pragma unroll
        for (int r = 0; r < RPW; ++r) {
            const int row = base + r;
            if (row < n_rows) {                      // wave-uniform guard
                float4 a = make_float4(0.f, 0.f, 0.f, 0.f);
                #pragma unroll
                for (int k = 0; k < L; ++k) {
                    const int d  = r * L + k;        // 0..319, compile-time
                    const int id = __builtin_amdgcn_readlane(g[d >> 6], d & 63);
                    a.x += (id == s0) ? pw[k] : 0.f; // v_cmp+cndmask+add
                    a.y += (id == s1) ? pw[k] : 0.f;
                    a.z += (id == s2) ? pw[k] : 0.f;
                    a.w += (id == s3) ? pw[k] : 0.f;
                }
                out4[(size_t)row * (VOCAB / 4) + lane] = a;
            }
        }
    }
}

extern "C" void kernel_launch(void* const* d_in, const int* in_sizes, int n_in,
                              void* d_out, int out_size, void* d_ws, size_t ws_size,
                              hipStream_t stream) {
    const int*   char_ids = (const int*)d_in[0];
    const float* alpha    = (const float*)d_in[1];
    float*       out      = (float*)d_out;
    const int    n_rows   = in_sizes[0] / L;   // 131072

    fofe_kernel<<<GRID, BLOCK, 0, stream>>>(char_ids, alpha, out, n_rows);
}